// Round 5
// baseline (1799.230 us; speedup 1.0000x reference)
//
#include <hip/hip_runtime.h>
#include <math.h>

// SimpleRNN: out[b,t,u] = h_t where h_t = tanh(x_t @ Wx + bias + h_{t-1} @ Wh)
// Phase 1: xp = x @ Wx + bias  -> workspace (d_ws)
// Phase 0: out prefilled with sentinel bytes 0xFF (-NaN; tanh never produces it)
// Phase 2: rnn_scan5 -- 256 blocks = 4 u-slices x 64 batch-groups (2 batches), 1024 thr.
//   Group members are blockIdx {bg, bg+64, bg+128, bg+192} -> same XCD under the
//   %8 round-robin dispatch (perf heuristic only; agent-scope atomics keep it
//   correct under any mapping).
//   Wh[:,128-slice] in 16 pinned float4 (lives in unified VGPR/AGPR file).
//   No h staging phase: each thread atomically loads the 16 h values of its own
//   k-range per batch straight from out[] (data-as-flag, batch-pass straggler
//   fixup). Waves skew independently through poll+FMA; 2 barriers/step.

#define BM 64
#define BN 64
#define BK 32
#define SENT 0xFFFFFFFFu
#define AL(p) __hip_atomic_load((p), __ATOMIC_RELAXED, __HIP_MEMORY_SCOPE_AGENT)
#define AS(p, v) __hip_atomic_store((p), (v), __ATOMIC_RELAXED, __HIP_MEMORY_SCOPE_AGENT)

__global__ __launch_bounds__(256) void xp_gemm(
    const float* __restrict__ x,    // [65536, 256]
    const float* __restrict__ wx,   // [256, 512]
    const float* __restrict__ bias, // [512]
    float* __restrict__ xp)         // [65536, 512] (workspace)
{
    __shared__ float As[BK][BM + 4];
    __shared__ float Bs[BK][BN + 4];

    const int tid = threadIdx.x;
    const int m0 = blockIdx.y * BM;
    const int n0 = blockIdx.x * BN;
    const int tm = tid / 16;
    const int tn = tid % 16;

    float acc[4][4] = {};

    for (int k0 = 0; k0 < 256; k0 += BK) {
        {
            const int kk = tid % BK;
            const int r0 = tid / BK;
            #pragma unroll
            for (int rr = 0; rr < 8; ++rr) {
                const int m = r0 + rr * 8;
                As[kk][m] = x[(size_t)(m0 + m) * 256 + (k0 + kk)];
            }
        }
        {
            const int nn = tid % BN;
            const int r0 = tid / BN;
            #pragma unroll
            for (int rr = 0; rr < 8; ++rr) {
                const int k = r0 + rr * 4;
                Bs[k][nn] = wx[(size_t)(k0 + k) * 512 + (n0 + nn)];
            }
        }
        __syncthreads();

        #pragma unroll
        for (int kk = 0; kk < BK; ++kk) {
            const float4 a = *(const float4*)&As[kk][tm * 4];
            const float4 b = *(const float4*)&Bs[kk][tn * 4];
            const float av[4] = {a.x, a.y, a.z, a.w};
            const float bv[4] = {b.x, b.y, b.z, b.w};
            #pragma unroll
            for (int i = 0; i < 4; ++i)
                #pragma unroll
                for (int j = 0; j < 4; ++j)
                    acc[i][j] += av[i] * bv[j];
        }
        __syncthreads();
    }

    #pragma unroll
    for (int i = 0; i < 4; ++i) {
        const int m = m0 + tm * 4 + i;
        #pragma unroll
        for (int j = 0; j < 4; ++j) {
            const int n = n0 + tn * 4 + j;
            xp[(size_t)m * 512 + n] = acc[i][j] + bias[n];
        }
    }
}

#define FMA4(A, W, H) { (A).x += (H)*(W).x; (A).y += (H)*(W).y; (A).z += (H)*(W).z; (A).w += (H)*(W).w; }
#define PIN4(W) asm volatile("" : "+v"((W).x), "+v"((W).y), "+v"((W).z), "+v"((W).w))

__global__ __launch_bounds__(1024, 4) void rnn_scan5(
    const float* __restrict__ wh,   // [512, 512] row-major (k, u)
    const float* __restrict__ xp,   // [128, 512, 512] (workspace)
    float* __restrict__ out)        // [128, 512, 512] sentinel-prefilled; h written here
{
    __shared__ float red[32][2][128];      // 32 KB

    const int tid = threadIdx.x;
    const int us  = blockIdx.x >> 6;   // u-slice 0..3   (stride-64 grouping -> same XCD)
    const int bg  = blockIdx.x & 63;   // batch-group 0..63
    const int u0  = us * 128;
    const int g   = tid & 31;          // u-quad: u = u0+4g .. u0+4g+3
    const int s   = tid >> 5;          // k-slice: k = 16s .. 16s+15
    const int kbase = s * 16;
    const size_t seq = 512 * 512;

    // ---- Wh slice in 16 pinned float4 (unified VGPR/AGPR residency) ----
    const float* wr = &wh[(size_t)kbase * 512 + (u0 + 4 * g)];
    float4 w0  = *(const float4*)(wr + 0  * 512);
    float4 w1  = *(const float4*)(wr + 1  * 512);
    float4 w2  = *(const float4*)(wr + 2  * 512);
    float4 w3  = *(const float4*)(wr + 3  * 512);
    float4 w4  = *(const float4*)(wr + 4  * 512);
    float4 w5  = *(const float4*)(wr + 5  * 512);
    float4 w6  = *(const float4*)(wr + 6  * 512);
    float4 w7  = *(const float4*)(wr + 7  * 512);
    float4 w8  = *(const float4*)(wr + 8  * 512);
    float4 w9  = *(const float4*)(wr + 9  * 512);
    float4 w10 = *(const float4*)(wr + 10 * 512);
    float4 w11 = *(const float4*)(wr + 11 * 512);
    float4 w12 = *(const float4*)(wr + 12 * 512);
    float4 w13 = *(const float4*)(wr + 13 * 512);
    float4 w14 = *(const float4*)(wr + 14 * 512);
    float4 w15 = *(const float4*)(wr + 15 * 512);
    PIN4(w0);  PIN4(w1);  PIN4(w2);  PIN4(w3);
    PIN4(w4);  PIN4(w5);  PIN4(w6);  PIN4(w7);
    PIN4(w8);  PIN4(w9);  PIN4(w10); PIN4(w11);
    PIN4(w12); PIN4(w13); PIN4(w14); PIN4(w15);

    // reduce role (tid < 256): output unit u0+ru of batch rb
    const int ru = tid & 127;
    const int rb = (tid >> 7) & 1;
    const float* xpp = xp + (size_t)(bg * 2 + rb) * seq + u0 + ru;   // + t*512
    float*       hop = out + (size_t)(bg * 2 + rb) * seq + u0 + ru;  // + t*512

    // per-thread h sources (own k-range, both batches of the group)
    const float* h0base = out + (size_t)(bg * 2 + 0) * seq + kbase;  // + (t-1)*512
    const float* h1base = out + (size_t)(bg * 2 + 1) * seq + kbase;

    // ---- t = 0: h_{-1} = 0  =>  h_0 = tanh(xp_0) ----
    if (tid < 256) {
        AS(hop, tanhf(xpp[0]));
    }
    // no barrier: downstream consumers poll

    for (int t = 1; t < 512; ++t) {
        float xpv = 0.0f;
        if (tid < 256) xpv = xpp[(size_t)t * 512];   // issued early, used post-reduce

        const float* s0 = h0base + (size_t)(t - 1) * 512;
        const float* s1 = h1base + (size_t)(t - 1) * 512;

        // issue all 32 h loads (2 chunks x 2 batches) -- independent, in flight together
        float hA0[8], hA1[8], hB0[8], hB1[8];
        #pragma unroll
        for (int i = 0; i < 8; ++i) hA0[i] = AL(s0 + i);
        #pragma unroll
        for (int i = 0; i < 8; ++i) hA1[i] = AL(s1 + i);
        #pragma unroll
        for (int i = 0; i < 8; ++i) hB0[i] = AL(s0 + 8 + i);
        #pragma unroll
        for (int i = 0; i < 8; ++i) hB1[i] = AL(s1 + 8 + i);

        float4 a0 = make_float4(0.f, 0.f, 0.f, 0.f);
        float4 a1 = make_float4(0.f, 0.f, 0.f, 0.f);

        // ---- chunk A: straggler fixup (batch-pass, loads re-issued in parallel) ----
        for (int pass = 0; pass < (1 << 20); ++pass) {
            unsigned bad = 0;
            #pragma unroll
            for (int i = 0; i < 8; ++i)
                bad |= (unsigned)(__float_as_uint(hA0[i]) == SENT)
                     | (unsigned)(__float_as_uint(hA1[i]) == SENT);
            if (!bad) break;
            if (pass > 4) __builtin_amdgcn_s_sleep(1);
            #pragma unroll
            for (int i = 0; i < 8; ++i) {
                if (__float_as_uint(hA0[i]) == SENT) hA0[i] = AL(s0 + i);
                if (__float_as_uint(hA1[i]) == SENT) hA1[i] = AL(s1 + i);
            }
        }
        FMA4(a0, w0, hA0[0]) FMA4(a0, w1, hA0[1]) FMA4(a0, w2, hA0[2]) FMA4(a0, w3, hA0[3])
        FMA4(a0, w4, hA0[4]) FMA4(a0, w5, hA0[5]) FMA4(a0, w6, hA0[6]) FMA4(a0, w7, hA0[7])
        FMA4(a1, w0, hA1[0]) FMA4(a1, w1, hA1[1]) FMA4(a1, w2, hA1[2]) FMA4(a1, w3, hA1[3])
        FMA4(a1, w4, hA1[4]) FMA4(a1, w5, hA1[5]) FMA4(a1, w6, hA1[6]) FMA4(a1, w7, hA1[7])

        // ---- chunk B: fixup + FMA ----
        for (int pass = 0; pass < (1 << 20); ++pass) {
            unsigned bad = 0;
            #pragma unroll
            for (int i = 0; i < 8; ++i)
                bad |= (unsigned)(__float_as_uint(hB0[i]) == SENT)
                     | (unsigned)(__float_as_uint(hB1[i]) == SENT);
            if (!bad) break;
            if (pass > 4) __builtin_amdgcn_s_sleep(1);
            #pragma unroll
            for (int i = 0; i < 8; ++i) {
                if (__float_as_uint(hB0[i]) == SENT) hB0[i] = AL(s0 + 8 + i);
                if (__float_as_uint(hB1[i]) == SENT) hB1[i] = AL(s1 + 8 + i);
            }
        }
        FMA4(a0, w8,  hB0[0]) FMA4(a0, w9,  hB0[1]) FMA4(a0, w10, hB0[2]) FMA4(a0, w11, hB0[3])
        FMA4(a0, w12, hB0[4]) FMA4(a0, w13, hB0[5]) FMA4(a0, w14, hB0[6]) FMA4(a0, w15, hB0[7])
        FMA4(a1, w8,  hB1[0]) FMA4(a1, w9,  hB1[1]) FMA4(a1, w10, hB1[2]) FMA4(a1, w11, hB1[3])
        FMA4(a1, w12, hB1[4]) FMA4(a1, w13, hB1[5]) FMA4(a1, w14, hB1[6]) FMA4(a1, w15, hB1[7])

        *(float4*)&red[s][0][4 * g] = a0;
        *(float4*)&red[s][1][4 * g] = a1;
        __syncthreads();   // partials ready

        if (tid < 256) {
            float r = xpv;
            #pragma unroll
            for (int ss = 0; ss < 32; ++ss) r += red[ss][rb][ru];
            const float hn = tanhf(r);
            AS(hop + (size_t)t * 512, hn);   // publish h_t (data IS the flag)
        }
        __syncthreads();   // red safe to overwrite next step
    }
}

// ---- fallback: flag-sync version (ws >= 128 KB but < 128 MB) ----
__global__ __launch_bounds__(1024) void rnn_scan3(
    const float* __restrict__ wh, float* __restrict__ out, int* __restrict__ flags)
{
    __shared__ float smem[21504];
    float* h_lds = smem;
    float* red   = smem + 1024;

    const int tid = threadIdx.x;
    const int us  = blockIdx.x & 3;
    const int bg  = blockIdx.x >> 2;
    const int u0  = us * 128;
    const int g   = tid & 31;
    const int s   = tid >> 5;
    const int kbase = s * 16;

    float4 w[16];
    #pragma unroll
    for (int i = 0; i < 16; ++i)
        w[i] = *(const float4*)&wh[(size_t)(kbase + i) * 512 + (u0 + 4 * g)];

    float* out0 = out + (size_t)(bg * 2 + 0) * (512 * 512);
    float* out1 = out + (size_t)(bg * 2 + 1) * (512 * 512);
    const int ru = tid & 127;
    const int rb = tid >> 7;
    int* myflag = flags + bg * 512;

    for (int t = 0; t < 512; ++t) {
        float xpv = 0.f;
        if (tid < 256) {
            const float* op = (rb == 0) ? out0 : out1;
            xpv = op[(size_t)t * 512 + u0 + ru];
        }
        if (t == 0) {
            h_lds[tid] = 0.f;
        } else {
            if (tid == 0) {
                int v, cnt = 0;
                do {
                    v = __hip_atomic_load(&myflag[t - 1], __ATOMIC_RELAXED, __HIP_MEMORY_SCOPE_AGENT);
                    if (v < 4) __builtin_amdgcn_s_sleep(2);
                } while (v < 4 && ++cnt < (1 << 22));
                (void)__hip_atomic_load(&myflag[t - 1], __ATOMIC_ACQUIRE, __HIP_MEMORY_SCOPE_AGENT);
            }
            __syncthreads();
            const int hb = tid >> 9;
            const int hk = tid & 511;
            const float* src = ((hb == 0) ? out0 : out1) + (size_t)(t - 1) * 512 + hk;
            h_lds[hb * 512 + hk] = __hip_atomic_load(src, __ATOMIC_RELAXED, __HIP_MEMORY_SCOPE_AGENT);
        }
        __syncthreads();

        float4 a0 = make_float4(0.f, 0.f, 0.f, 0.f);
        float4 a1 = make_float4(0.f, 0.f, 0.f, 0.f);
        #pragma unroll
        for (int i = 0; i < 4; ++i) {
            const float4 h0 = *(const float4*)&h_lds[0 * 512 + kbase + 4 * i];
            const float4 h1 = *(const float4*)&h_lds[1 * 512 + kbase + 4 * i];
            FMA4(a0, w[4*i+0], h0.x) FMA4(a0, w[4*i+1], h0.y) FMA4(a0, w[4*i+2], h0.z) FMA4(a0, w[4*i+3], h0.w)
            FMA4(a1, w[4*i+0], h1.x) FMA4(a1, w[4*i+1], h1.y) FMA4(a1, w[4*i+2], h1.z) FMA4(a1, w[4*i+3], h1.w)
        }
        *(float4*)&red[(s * 2 + 0) * 128 + 4 * g] = a0;
        *(float4*)&red[(s * 2 + 1) * 128 + 4 * g] = a1;
        __syncthreads();

        if (tid < 256) {
            float r = xpv;
            #pragma unroll
            for (int ss = 0; ss < 32; ++ss) r += red[(ss * 2 + rb) * 128 + ru];
            const float hn = tanhf(r);
            float* op = (rb == 0) ? out0 : out1;
            __hip_atomic_store(&op[(size_t)t * 512 + u0 + ru], hn,
                               __ATOMIC_RELAXED, __HIP_MEMORY_SCOPE_AGENT);
        }
        __syncthreads();
        if (tid == 0)
            __hip_atomic_fetch_add(&myflag[t], 1, __ATOMIC_RELEASE, __HIP_MEMORY_SCOPE_AGENT);
    }
}

// ---- fallback: single-block-per-pair version (no usable ws) ----
__global__ __launch_bounds__(1024, 4) void rnn_scan2(
    const float* __restrict__ wh, float* __restrict__ out)
{
    __shared__ float h_lds[2][512];
    __shared__ float red[8][2][512];

    const int tid = threadIdx.x;
    const int g = tid & 127;
    const int s = tid >> 7;
    const int b = tid >> 9;
    const int u = tid & 511;

    float* seqb = out + (size_t)(2 * blockIdx.x + b) * 512 * 512;
    h_lds[b][u] = 0.0f;
    __syncthreads();

    const float4* __restrict__ whv = (const float4*)wh;
    const int kbase = s * 64;

    for (int t = 0; t < 512; ++t) {
        const float xpv = seqb[(size_t)t * 512 + u];
        float4 a0 = make_float4(0.f, 0.f, 0.f, 0.f);
        float4 a1 = make_float4(0.f, 0.f, 0.f, 0.f);
        #pragma unroll 4
        for (int kk = 0; kk < 64; kk += 4) {
            const int k = kbase + kk;
            const float4 h0 = *(const float4*)&h_lds[0][k];
            const float4 h1 = *(const float4*)&h_lds[1][k];
            const float4 v0 = whv[(k + 0) * 128 + g];
            const float4 v1 = whv[(k + 1) * 128 + g];
            const float4 v2 = whv[(k + 2) * 128 + g];
            const float4 v3 = whv[(k + 3) * 128 + g];
            FMA4(a0, v0, h0.x) FMA4(a0, v1, h0.y) FMA4(a0, v2, h0.z) FMA4(a0, v3, h0.w)
            FMA4(a1, v0, h1.x) FMA4(a1, v1, h1.y) FMA4(a1, v2, h1.z) FMA4(a1, v3, h1.w)
        }
        *(float4*)&red[s][0][4 * g] = a0;
        *(float4*)&red[s][1][4 * g] = a1;
        __syncthreads();
        float r = xpv;
        #pragma unroll
        for (int ss = 0; ss < 8; ++ss) r += red[ss][b][u];
        const float hn = tanhf(r);
        h_lds[b][u] = hn;
        seqb[(size_t)t * 512 + u] = hn;
        __syncthreads();
    }
}

extern "C" void kernel_launch(void* const* d_in, const int* in_sizes, int n_in,
                              void* d_out, int out_size, void* d_ws, size_t ws_size,
                              hipStream_t stream) {
    const float* x    = (const float*)d_in[0];  // [128,512,256]
    const float* wx   = (const float*)d_in[1];  // [256,512]
    const float* wh   = (const float*)d_in[2];  // [512,512]
    const float* bias = (const float*)d_in[3];  // [512]
    float* out = (float*)d_out;                 // [128,512,512]

    dim3 g1(512 / BN, 65536 / BM);
    const size_t xp_bytes = (size_t)128 * 512 * 512 * sizeof(float);
    const size_t flag_bytes = 64 * 512 * sizeof(int);

    if (d_ws != nullptr && ws_size >= xp_bytes) {
        // Primary path: xp in workspace, out sentinel-filled, data-as-flag scan.
        hipMemsetAsync(d_out, 0xFF, xp_bytes, stream);
        xp_gemm<<<g1, 256, 0, stream>>>(x, wx, bias, (float*)d_ws);
        rnn_scan5<<<256, 1024, 0, stream>>>(wh, (const float*)d_ws, out);
    } else if (d_ws != nullptr && ws_size >= flag_bytes) {
        hipMemsetAsync(d_ws, 0, flag_bytes, stream);
        xp_gemm<<<g1, 256, 0, stream>>>(x, wx, bias, out);
        rnn_scan3<<<256, 1024, 0, stream>>>(wh, out, (int*)d_ws);
    } else {
        xp_gemm<<<g1, 256, 0, stream>>>(x, wx, bias, out);
        rnn_scan2<<<64, 1024, 0, stream>>>(wh, out);
    }
}

// Round 6
// 1560.256 us; speedup vs baseline: 1.1532x; 1.1532x over previous
//
#include <hip/hip_runtime.h>
#include <math.h>

// SimpleRNN: out[b,t,u] = h_t where h_t = tanh(x_t @ Wx + bias + h_{t-1} @ Wh)
// Phase 1: xp = x @ Wx + bias  -> workspace (d_ws)
// Phase 0: out prefilled with sentinel bytes 0xFF (-NaN; tanh never produces it)
// Phase 2: rnn_scan6 -- 256 blocks = 8 u-slices(64) x 32 groups(4 batches), 1024 thr.
//   Group g's 8 blocks are blockIdx {g, g+32, ..., g+224} == g (mod 8) -> same XCD
//   under %8 round-robin (heuristic only; agent atomics keep it correct anyway).
//   2-deep batch stagger: pair A = batches {4g+0,4g+1}, pair B = {4g+2,4g+3}.
//   phase(A,t) computes while B's h(t-1) round trip is in flight and vice versa
//   -> the ~1.2-1.4 us producer->L2->consumer latency (the R4 wall) is hidden.
//   Wh[:,64-slice] in 8 pinned float4/thread; h deduped through LDS staging
//   (R5 lesson: never replicate agent-scope loads per-thread).

#define BM 64
#define BN 64
#define BK 32
#define SENT 0xFFFFFFFFu
#define AL(p) __hip_atomic_load((p), __ATOMIC_RELAXED, __HIP_MEMORY_SCOPE_AGENT)
#define AS(p, v) __hip_atomic_store((p), (v), __ATOMIC_RELAXED, __HIP_MEMORY_SCOPE_AGENT)

__global__ __launch_bounds__(256) void xp_gemm(
    const float* __restrict__ x,    // [65536, 256]
    const float* __restrict__ wx,   // [256, 512]
    const float* __restrict__ bias, // [512]
    float* __restrict__ xp)         // [65536, 512] (workspace)
{
    __shared__ float As[BK][BM + 4];
    __shared__ float Bs[BK][BN + 4];

    const int tid = threadIdx.x;
    const int m0 = blockIdx.y * BM;
    const int n0 = blockIdx.x * BN;
    const int tm = tid / 16;
    const int tn = tid % 16;

    float acc[4][4] = {};

    for (int k0 = 0; k0 < 256; k0 += BK) {
        {
            const int kk = tid % BK;
            const int r0 = tid / BK;
            #pragma unroll
            for (int rr = 0; rr < 8; ++rr) {
                const int m = r0 + rr * 8;
                As[kk][m] = x[(size_t)(m0 + m) * 256 + (k0 + kk)];
            }
        }
        {
            const int nn = tid % BN;
            const int r0 = tid / BN;
            #pragma unroll
            for (int rr = 0; rr < 8; ++rr) {
                const int k = r0 + rr * 4;
                Bs[k][nn] = wx[(size_t)(k0 + k) * 512 + (n0 + nn)];
            }
        }
        __syncthreads();

        #pragma unroll
        for (int kk = 0; kk < BK; ++kk) {
            const float4 a = *(const float4*)&As[kk][tm * 4];
            const float4 b = *(const float4*)&Bs[kk][tn * 4];
            const float av[4] = {a.x, a.y, a.z, a.w};
            const float bv[4] = {b.x, b.y, b.z, b.w};
            #pragma unroll
            for (int i = 0; i < 4; ++i)
                #pragma unroll
                for (int j = 0; j < 4; ++j)
                    acc[i][j] += av[i] * bv[j];
        }
        __syncthreads();
    }

    #pragma unroll
    for (int i = 0; i < 4; ++i) {
        const int m = m0 + tm * 4 + i;
        #pragma unroll
        for (int j = 0; j < 4; ++j) {
            const int n = n0 + tn * 4 + j;
            xp[(size_t)m * 512 + n] = acc[i][j] + bias[n];
        }
    }
}

#define FMA4(A, W, H) { (A).x += (H)*(W).x; (A).y += (H)*(W).y; (A).z += (H)*(W).z; (A).w += (H)*(W).w; }
#define PIN4(W) asm volatile("" : "+v"((W).x), "+v"((W).y), "+v"((W).z), "+v"((W).w))

__global__ __launch_bounds__(1024, 4) void rnn_scan6(
    const float* __restrict__ wh,   // [512, 512] row-major (k, u)
    const float* __restrict__ xp,   // [128, 512, 512] (workspace)
    float* __restrict__ out)        // [128, 512, 512] sentinel-prefilled; h written here
{
    __shared__ float h_stage[2][2][512];   // [pair][batch][k]   8 KB
    __shared__ float red[64][2][64];       // [k-slice][batch][u] 32 KB
    __shared__ float red2[8][2][64];       // level-1 partials     4 KB

    const int tid = threadIdx.x;
    const int us  = blockIdx.x >> 5;   // u-slice 0..7
    const int bg  = blockIdx.x & 31;   // batch-group 0..31 (same XCD across slices)
    const int u0  = us * 64;
    const int g   = tid & 15;          // u-quad: u = u0+4g .. u0+4g+3
    const int s   = tid >> 4;          // k-slice 0..63: k = 8s .. 8s+7
    const int kbase = s * 8;
    const size_t seq = 512 * 512;
    const int bgbase = bg * 4;

    // ---- Wh slice: 8 pinned float4 (32 regs) ----
    const float* wr = &wh[(size_t)kbase * 512 + (u0 + 4 * g)];
    float4 w0 = *(const float4*)(wr + 0 * 512);
    float4 w1 = *(const float4*)(wr + 1 * 512);
    float4 w2 = *(const float4*)(wr + 2 * 512);
    float4 w3 = *(const float4*)(wr + 3 * 512);
    float4 w4 = *(const float4*)(wr + 4 * 512);
    float4 w5 = *(const float4*)(wr + 5 * 512);
    float4 w6 = *(const float4*)(wr + 6 * 512);
    float4 w7 = *(const float4*)(wr + 7 * 512);
    PIN4(w0); PIN4(w1); PIN4(w2); PIN4(w3);
    PIN4(w4); PIN4(w5); PIN4(w6); PIN4(w7);

    // stage role: thread -> (batch-in-pair, k)
    const int sb = tid >> 9;           // 0/1
    const int sk = tid & 511;          // 0..511
    // reduce roles
    const int j   = tid >> 7;          // level-1 chunk 0..7
    const int rb  = (tid >> 6) & 1;    // batch-in-pair
    const int ru  = tid & 63;          // u offset in slice

    // ---- t = 0: h_{-1}=0 => h_0 = tanh(xp_0); publish own slice for all 4 batches ----
    if (tid < 256) {
        const int b  = tid >> 6;                 // 0..3
        const size_t off = (size_t)(bgbase + b) * seq + (u0 + (tid & 63));
        AS(out + off, tanhf(xp[off]));
    }
    // no barrier needed: everything downstream polls

    for (int t = 1; t < 512; ++t) {
        #pragma unroll
        for (int P = 0; P < 2; ++P) {
            // xp prefetch for the publisher role (used after reduce)
            float xpv = 0.0f;
            if (tid < 128)
                xpv = xp[(size_t)(bgbase + 2 * P + rb) * seq + (size_t)t * 512 + u0 + ru];

            // ---- stage h_P(t-1): one value per thread, data-as-flag poll ----
            {
                const float* p = out + (size_t)(bgbase + 2 * P + sb) * seq
                               + (size_t)(t - 1) * 512 + sk;
                float v = AL(p);
                int it = 0;
                while (__float_as_uint(v) == SENT && ++it < (1 << 20)) {
                    if (it > 8) __builtin_amdgcn_s_sleep(1);
                    v = AL(p);
                }
                h_stage[P][sb][sk] = v;
            }
            __syncthreads();   // h staged

            // ---- FMA: 8k x 4u x 2 batches against pinned weights ----
            float4 a0 = make_float4(0.f, 0.f, 0.f, 0.f);
            float4 a1 = make_float4(0.f, 0.f, 0.f, 0.f);
            {
                const float* hb0 = &h_stage[P][0][kbase];
                const float* hb1 = &h_stage[P][1][kbase];
                const float4 h0a = *(const float4*)(hb0);
                const float4 h0b = *(const float4*)(hb0 + 4);
                const float4 h1a = *(const float4*)(hb1);
                const float4 h1b = *(const float4*)(hb1 + 4);
                FMA4(a0, w0, h0a.x) FMA4(a0, w1, h0a.y) FMA4(a0, w2, h0a.z) FMA4(a0, w3, h0a.w)
                FMA4(a0, w4, h0b.x) FMA4(a0, w5, h0b.y) FMA4(a0, w6, h0b.z) FMA4(a0, w7, h0b.w)
                FMA4(a1, w0, h1a.x) FMA4(a1, w1, h1a.y) FMA4(a1, w2, h1a.z) FMA4(a1, w3, h1a.w)
                FMA4(a1, w4, h1b.x) FMA4(a1, w5, h1b.y) FMA4(a1, w6, h1b.z) FMA4(a1, w7, h1b.w)
            }
            *(float4*)&red[s][0][4 * g] = a0;
            *(float4*)&red[s][1][4 * g] = a1;
            __syncthreads();   // partials ready

            // ---- level-1 reduce: 1024 threads, 8 deep ----
            {
                float r1 = 0.f;
                #pragma unroll
                for (int i = 0; i < 8; ++i) r1 += red[8 * j + i][rb][ru];
                red2[j][rb][ru] = r1;
            }
            __syncthreads();   // red2 ready

            // ---- level-2 reduce + tanh + publish (data IS the flag) ----
            if (tid < 128) {
                float r = xpv;
                #pragma unroll
                for (int jj = 0; jj < 8; ++jj) r += red2[jj][rb][ru];
                AS(out + (size_t)(bgbase + 2 * P + rb) * seq + (size_t)t * 512 + (u0 + ru),
                   tanhf(r));
            }
            // no 4th barrier: red is next written only after the next phase's
            // post-stage __syncthreads, red2 only after its post-FMA one.
        }
    }
}

// ---- fallback: flag-sync version (ws >= 128 KB but < 128 MB) ----
__global__ __launch_bounds__(1024) void rnn_scan3(
    const float* __restrict__ wh, float* __restrict__ out, int* __restrict__ flags)
{
    __shared__ float smem[21504];
    float* h_lds = smem;
    float* red   = smem + 1024;

    const int tid = threadIdx.x;
    const int us  = blockIdx.x & 3;
    const int bg  = blockIdx.x >> 2;
    const int u0  = us * 128;
    const int g   = tid & 31;
    const int s   = tid >> 5;
    const int kbase = s * 16;

    float4 w[16];
    #pragma unroll
    for (int i = 0; i < 16; ++i)
        w[i] = *(const float4*)&wh[(size_t)(kbase + i) * 512 + (u0 + 4 * g)];

    float* out0 = out + (size_t)(bg * 2 + 0) * (512 * 512);
    float* out1 = out + (size_t)(bg * 2 + 1) * (512 * 512);
    const int ru = tid & 127;
    const int rb = tid >> 7;
    int* myflag = flags + bg * 512;

    for (int t = 0; t < 512; ++t) {
        float xpv = 0.f;
        if (tid < 256) {
            const float* op = (rb == 0) ? out0 : out1;
            xpv = op[(size_t)t * 512 + u0 + ru];
        }
        if (t == 0) {
            h_lds[tid] = 0.f;
        } else {
            if (tid == 0) {
                int v, cnt = 0;
                do {
                    v = __hip_atomic_load(&myflag[t - 1], __ATOMIC_RELAXED, __HIP_MEMORY_SCOPE_AGENT);
                    if (v < 4) __builtin_amdgcn_s_sleep(2);
                } while (v < 4 && ++cnt < (1 << 22));
                (void)__hip_atomic_load(&myflag[t - 1], __ATOMIC_ACQUIRE, __HIP_MEMORY_SCOPE_AGENT);
            }
            __syncthreads();
            const int hb = tid >> 9;
            const int hk = tid & 511;
            const float* src = ((hb == 0) ? out0 : out1) + (size_t)(t - 1) * 512 + hk;
            h_lds[hb * 512 + hk] = __hip_atomic_load(src, __ATOMIC_RELAXED, __HIP_MEMORY_SCOPE_AGENT);
        }
        __syncthreads();

        float4 a0 = make_float4(0.f, 0.f, 0.f, 0.f);
        float4 a1 = make_float4(0.f, 0.f, 0.f, 0.f);
        #pragma unroll
        for (int i = 0; i < 4; ++i) {
            const float4 h0 = *(const float4*)&h_lds[0 * 512 + kbase + 4 * i];
            const float4 h1 = *(const float4*)&h_lds[1 * 512 + kbase + 4 * i];
            FMA4(a0, w[4*i+0], h0.x) FMA4(a0, w[4*i+1], h0.y) FMA4(a0, w[4*i+2], h0.z) FMA4(a0, w[4*i+3], h0.w)
            FMA4(a1, w[4*i+0], h1.x) FMA4(a1, w[4*i+1], h1.y) FMA4(a1, w[4*i+2], h1.z) FMA4(a1, w[4*i+3], h1.w)
        }
        *(float4*)&red[(s * 2 + 0) * 128 + 4 * g] = a0;
        *(float4*)&red[(s * 2 + 1) * 128 + 4 * g] = a1;
        __syncthreads();

        if (tid < 256) {
            float r = xpv;
            #pragma unroll
            for (int ss = 0; ss < 32; ++ss) r += red[(ss * 2 + rb) * 128 + ru];
            const float hn = tanhf(r);
            float* op = (rb == 0) ? out0 : out1;
            __hip_atomic_store(&op[(size_t)t * 512 + u0 + ru], hn,
                               __ATOMIC_RELAXED, __HIP_MEMORY_SCOPE_AGENT);
        }
        __syncthreads();
        if (tid == 0)
            __hip_atomic_fetch_add(&myflag[t], 1, __ATOMIC_RELEASE, __HIP_MEMORY_SCOPE_AGENT);
    }
}

// ---- fallback: single-block-per-pair version (no usable ws) ----
__global__ __launch_bounds__(1024, 4) void rnn_scan2(
    const float* __restrict__ wh, float* __restrict__ out)
{
    __shared__ float h_lds[2][512];
    __shared__ float red[8][2][512];

    const int tid = threadIdx.x;
    const int g = tid & 127;
    const int s = tid >> 7;
    const int b = tid >> 9;
    const int u = tid & 511;

    float* seqb = out + (size_t)(2 * blockIdx.x + b) * 512 * 512;
    h_lds[b][u] = 0.0f;
    __syncthreads();

    const float4* __restrict__ whv = (const float4*)wh;
    const int kbase = s * 64;

    for (int t = 0; t < 512; ++t) {
        const float xpv = seqb[(size_t)t * 512 + u];
        float4 a0 = make_float4(0.f, 0.f, 0.f, 0.f);
        float4 a1 = make_float4(0.f, 0.f, 0.f, 0.f);
        #pragma unroll 4
        for (int kk = 0; kk < 64; kk += 4) {
            const int k = kbase + kk;
            const float4 h0 = *(const float4*)&h_lds[0][k];
            const float4 h1 = *(const float4*)&h_lds[1][k];
            const float4 v0 = whv[(k + 0) * 128 + g];
            const float4 v1 = whv[(k + 1) * 128 + g];
            const float4 v2 = whv[(k + 2) * 128 + g];
            const float4 v3 = whv[(k + 3) * 128 + g];
            FMA4(a0, v0, h0.x) FMA4(a0, v1, h0.y) FMA4(a0, v2, h0.z) FMA4(a0, v3, h0.w)
            FMA4(a1, v0, h1.x) FMA4(a1, v1, h1.y) FMA4(a1, v2, h1.z) FMA4(a1, v3, h1.w)
        }
        *(float4*)&red[s][0][4 * g] = a0;
        *(float4*)&red[s][1][4 * g] = a1;
        __syncthreads();
        float r = xpv;
        #pragma unroll
        for (int ss = 0; ss < 8; ++ss) r += red[ss][b][u];
        const float hn = tanhf(r);
        h_lds[b][u] = hn;
        seqb[(size_t)t * 512 + u] = hn;
        __syncthreads();
    }
}

extern "C" void kernel_launch(void* const* d_in, const int* in_sizes, int n_in,
                              void* d_out, int out_size, void* d_ws, size_t ws_size,
                              hipStream_t stream) {
    const float* x    = (const float*)d_in[0];  // [128,512,256]
    const float* wx   = (const float*)d_in[1];  // [256,512]
    const float* wh   = (const float*)d_in[2];  // [512,512]
    const float* bias = (const float*)d_in[3];  // [512]
    float* out = (float*)d_out;                 // [128,512,512]

    dim3 g1(512 / BN, 65536 / BM);
    const size_t xp_bytes = (size_t)128 * 512 * 512 * sizeof(float);
    const size_t flag_bytes = 64 * 512 * sizeof(int);

    if (d_ws != nullptr && ws_size >= xp_bytes) {
        // Primary path: xp in workspace, out sentinel-filled, data-as-flag scan.
        hipMemsetAsync(d_out, 0xFF, xp_bytes, stream);
        xp_gemm<<<g1, 256, 0, stream>>>(x, wx, bias, (float*)d_ws);
        rnn_scan6<<<256, 1024, 0, stream>>>(wh, (const float*)d_ws, out);
    } else if (d_ws != nullptr && ws_size >= flag_bytes) {
        hipMemsetAsync(d_ws, 0, flag_bytes, stream);
        xp_gemm<<<g1, 256, 0, stream>>>(x, wx, bias, out);
        rnn_scan3<<<256, 1024, 0, stream>>>(wh, out, (int*)d_ws);
    } else {
        xp_gemm<<<g1, 256, 0, stream>>>(x, wx, bias, out);
        rnn_scan2<<<64, 1024, 0, stream>>>(wh, out);
    }
}